// Round 22
// baseline (33.191 us; speedup 1.0000x reference)
//
#include <hip/hip_runtime.h>

#define B 256
#define N 2048
#define P 2048
#define C 10
#define S_CHUNKS 4
#define PPB (P / S_CHUNKS)     // 512 pairs per block
#define NIT (PPB / 32)         // 16 iterations; 32 pairs per block-iter
#define LN_EPS 1e-5f

typedef float v2f __attribute__((ext_vector_type(2)));
typedef _Float16 h2 __attribute__((ext_vector_type(2)));

// ---- f16 helpers (proven R11..R21) ------------------------------------------
static __device__ __forceinline__ float fdot2(h2 a, h2 b, float c) {
#if __has_builtin(__builtin_amdgcn_fdot2)
    return __builtin_amdgcn_fdot2(a, b, c, false);   // v_dot2_f32_f16
#else
    return (float)a.x * (float)b.x + (float)a.y * (float)b.y + c;
#endif
}
static __device__ __forceinline__ h2 h2fma(h2 a, h2 b, h2 c) {
#if __has_builtin(__builtin_elementwise_fma)
    return __builtin_elementwise_fma(a, b, c);        // v_pk_fma_f16
#else
    return a * b + c;
#endif
}
static __device__ __forceinline__ h2 h2relu(h2 x) {
#if __has_builtin(__builtin_elementwise_max)
    return __builtin_elementwise_max(x, h2{(_Float16)0.f, (_Float16)0.f});
#else
    h2 r;
    r.x = x.x > (_Float16)0.f ? x.x : (_Float16)0.f;
    r.y = x.y > (_Float16)0.f ? x.y : (_Float16)0.f;
    return r;
#endif
}
static __device__ __forceinline__ h2 pkrtz(float a, float b) {
#if __has_builtin(__builtin_amdgcn_cvt_pkrtz)
    return __builtin_bit_cast(h2, __builtin_amdgcn_cvt_pkrtz(a, b));
#else
    return h2{(_Float16)a, (_Float16)b};
#endif
}
static __device__ __forceinline__ unsigned pk_rne(float a, float b) {
    return __builtin_bit_cast(unsigned, h2{(_Float16)a, (_Float16)b});
}

// ---- 16-lane all-reduce sum via DPP butterfly (proven R2..R21) --------------
static __device__ __forceinline__ float red16(float x) {
    x += __int_as_float(__builtin_amdgcn_update_dpp(0, __float_as_int(x), 0xB1,  0xF, 0xF, true));
    x += __int_as_float(__builtin_amdgcn_update_dpp(0, __float_as_int(x), 0x4E,  0xF, 0xF, true));
    x += __int_as_float(__builtin_amdgcn_update_dpp(0, __float_as_int(x), 0x141, 0xF, 0xF, true));
    x += __int_as_float(__builtin_amdgcn_update_dpp(0, __float_as_int(x), 0x140, 0xF, 0xF, true));
    return x;
}

// ---------------------------------------------------------------------------
// Fused kernel (R20 body; the two per-iteration pair-streams are now computed
// by ONE interleaved proc2 with SEPARATE accumulators -- removes the
// cross-stream dependency through acc and adjacency-schedules both chains).
// ---------------------------------------------------------------------------
__global__ __launch_bounds__(256) void fused_kernel(
        const float* __restrict__ X,
        const float* __restrict__ W1, const float* __restrict__ b1,
        const float* __restrict__ gamma, const float* __restrict__ beta,
        const int*   __restrict__ pairs,
        float* __restrict__ part) {
    const int b = blockIdx.x;
    const int chunk = blockIdx.y;
    const int tid = threadIdx.x;
    const int w = tid >> 6, l = tid & 63, g = l >> 4, s = l & 15;
    const int slot = w * 4 + g;      // 0..15

    __shared__ __align__(16) float lds[4096];  // 16 KB: T stage + reduce alias
    __shared__ float wf[4][128];                // gamma-folded weights + beta
    __shared__ float sc[9];                     // S00,S11,Sbb,S01,S0b,S1b,m0,m1,mb
    uint2* Tl = (uint2*)lds;

    // ---- step 1: wave 0 computes the 9 scalars ----
    if (w == 0) {
        const float w0a = W1[l],       w0b = W1[l + 64];
        const float w1a = W1[128 + l], w1b = W1[128 + l + 64];
        const float bba = b1[l],       bbb = b1[l + 64];
        float s0 = w0a + w0b, s1 = w1a + w1b, sb = bba + bbb;
        #pragma unroll
        for (int m = 1; m < 64; m <<= 1) {
            s0 += __shfl_xor(s0, m);
            s1 += __shfl_xor(s1, m);
            sb += __shfl_xor(sb, m);
        }
        const float m0 = s0 * (1.f / 128.f);
        const float m1 = s1 * (1.f / 128.f);
        const float mb = sb * (1.f / 128.f);
        const float c0a = w0a - m0, c0b = w0b - m0;
        const float c1a = w1a - m1, c1b = w1b - m1;
        const float cba = bba - mb, cbb = bbb - mb;
        float q[6] = { c0a*c0a + c0b*c0b, c1a*c1a + c1b*c1b, cba*cba + cbb*cbb,
                       c0a*c1a + c0b*c1b, c0a*cba + c0b*cbb, c1a*cba + c1b*cbb };
        #pragma unroll
        for (int m = 1; m < 64; m <<= 1) {
            #pragma unroll
            for (int k = 0; k < 6; ++k) q[k] += __shfl_xor(q[k], m);
        }
        if (l < 6) sc[l] = q[l] * (1.f / 128.f);
        if (l == 6) sc[6] = m0;
        if (l == 7) sc[7] = m1;
        if (l == 8) sc[8] = mb;
    }
    __syncthreads();

    // ---- step 2a: weight arrays (f32) ----
    if (tid < 128) {
        const float m0 = sc[6], m1 = sc[7], mb = sc[8];
        const float g_ = gamma[tid];
        wf[0][tid] = g_ * (W1[tid] - m0);
        wf[1][tid] = g_ * (W1[128 + tid] - m1);
        wf[2][tid] = g_ * (b1[tid] - mb);
        wf[3][tid] = beta[tid];
    }

    // ---- step 2b: T slice for batch b, straight from X ----
    {
        const float S00 = sc[0], S11 = sc[1], Sbb = sc[2];
        const float S01 = sc[3], S0b = sc[4], S1b = sc[5];
        const float2* Xb = (const float2*)(X + (size_t)b * N * 2);
        #pragma unroll
        for (int q = 0; q < 8; ++q) {
            const int n = q * 256 + tid;
            const float2 x = Xb[n];
            const float v = fmaf(x.x * x.x, S00, fmaf(x.y * x.y, S11, Sbb))
                          + 2.f * fmaf(x.x * x.y, S01, fmaf(x.x, S0b, x.y * S1b));
            const float rs = rsqrtf(v + LN_EPS);
            Tl[n] = uint2{pk_rne(rs * x.x, rs * x.y), pk_rne(rs, 1.f)};
        }
    }
    __syncthreads();

    // ---- per-lane packed f16 weights from LDS ----
    h2 gw0[4], gw1[4], gbc[4], be2[4];
    #pragma unroll
    for (int m = 0; m < 4; ++m) {
        const int d0 = s + 32 * m, d1 = d0 + 16;
        gw0[m] = h2{(_Float16)wf[0][d0], (_Float16)wf[0][d1]};
        gw1[m] = h2{(_Float16)wf[1][d0], (_Float16)wf[1][d1]};
        gbc[m] = h2{(_Float16)wf[2][d0], (_Float16)wf[2][d1]};
        be2[m] = h2{(_Float16)wf[3][d0], (_Float16)wf[3][d1]};
    }

    const int4* pr4 = (const int4*)pairs;      // 2 pairs per int4
    const int i4base = chunk * (PPB / 2);

    v2f accA[4], accB[4];
    #pragma unroll
    for (int m = 0; m < 4; ++m) { accA[m] = v2f{0.f, 0.f}; accB[m] = v2f{0.f, 0.f}; }

    // both pair-streams computed in ONE interleaved region, separate accs
    auto proc2 = [&](const uint2 tiA, const uint2 tjA,
                     const uint2 tiB, const uint2 tjB) {
        const h2 abiA = __builtin_bit_cast(h2, tiA.x), ciA = __builtin_bit_cast(h2, tiA.y);
        const h2 abjA = __builtin_bit_cast(h2, tjA.x), cjA = __builtin_bit_cast(h2, tjA.y);
        const h2 abiB = __builtin_bit_cast(h2, tiB.x), ciB = __builtin_bit_cast(h2, tiB.y);
        const h2 abjB = __builtin_bit_cast(h2, tjB.x), cjB = __builtin_bit_cast(h2, tjB.y);
        const h2 aaiA = h2{abiA.x, abiA.x}, bbiA = h2{abiA.y, abiA.y}, cciA = h2{ciA.x, ciA.x};
        const h2 aajA = h2{abjA.x, abjA.x}, bbjA = h2{abjA.y, abjA.y}, ccjA = h2{cjA.x, cjA.x};
        const h2 aaiB = h2{abiB.x, abiB.x}, bbiB = h2{abiB.y, abiB.y}, cciB = h2{ciB.x, ciB.x};
        const h2 aajB = h2{abjB.x, abjB.x}, bbjB = h2{abjB.y, abjB.y}, ccjB = h2{cjB.x, cjB.x};
        h2 uuA[4], vvA[4], uuB[4], vvB[4];
        float nuA0 = 0.f, nuA1 = 0.f, nvA0 = 0.f, nvA1 = 0.f;
        float nuB0 = 0.f, nuB1 = 0.f, nvB0 = 0.f, nvB1 = 0.f;
        #pragma unroll
        for (int m = 0; m < 4; ++m) {
            const h2 hiA = h2relu(h2fma(aaiA, gw0[m], h2fma(bbiA, gw1[m], h2fma(cciA, gbc[m], be2[m]))));
            const h2 hjA = h2relu(h2fma(aajA, gw0[m], h2fma(bbjA, gw1[m], h2fma(ccjA, gbc[m], be2[m]))));
            const h2 hiB = h2relu(h2fma(aaiB, gw0[m], h2fma(bbiB, gw1[m], h2fma(cciB, gbc[m], be2[m]))));
            const h2 hjB = h2relu(h2fma(aajB, gw0[m], h2fma(bbjB, gw1[m], h2fma(ccjB, gbc[m], be2[m]))));
            const h2 uA = hiA - hjA, vA = hiA + hjA;
            const h2 uB = hiB - hjB, vB = hiB + hjB;
            if (m & 1) { nuA1 = fdot2(uA, uA, nuA1); nvA1 = fdot2(vA, vA, nvA1);
                         nuB1 = fdot2(uB, uB, nuB1); nvB1 = fdot2(vB, vB, nvB1); }
            else       { nuA0 = fdot2(uA, uA, nuA0); nvA0 = fdot2(vA, vA, nvA0);
                         nuB0 = fdot2(uB, uB, nuB0); nvB0 = fdot2(vB, vB, nvB0); }
            uuA[m] = uA; vvA[m] = vA;
            uuB[m] = uB; vvB[m] = vB;
        }
        const float nuA = red16(nuA0 + nuA1);
        const float nvA = red16(nvA0 + nvA1);
        const float nuB = red16(nuB0 + nuB1);
        const float nvB = red16(nvB0 + nvB1);
        const float ruA = rsqrtf(fmaxf(nuA, 1e-24f));
        const float rvA = rsqrtf(fmaxf(nvA, 1e-24f));
        const float ruB = rsqrtf(fmaxf(nuB, 1e-24f));
        const float rvB = rsqrtf(fmaxf(nvB, 1e-24f));
        const h2 ruvA = pkrtz(ruA, rvA);
        const h2 ruvB = pkrtz(ruB, rvB);
        #pragma unroll
        for (int m = 0; m < 4; ++m) {
            accA[m].x = fdot2(h2{uuA[m].x, vvA[m].x}, ruvA, accA[m].x);
            accA[m].y = fdot2(h2{uuA[m].y, vvA[m].y}, ruvA, accA[m].y);
            accB[m].x = fdot2(h2{uuB[m].x, vvB[m].x}, ruvB, accB[m].x);
            accB[m].y = fdot2(h2{uuB[m].y, vvB[m].y}, ruvB, accB[m].y);
        }
    };

    // ---- pipeline prologue (R14 structure) ----
    const int4 idx0 = pr4[i4base + slot];
    int4 idxN = pr4[i4base + 16 + slot];
    uint2 tiA = Tl[idx0.x], tjA = Tl[idx0.y];
    uint2 tiB = Tl[idx0.z], tjB = Tl[idx0.w];

    for (int t = 0; t < NIT; ++t) {
        const uint2 ntiA = Tl[idxN.x], ntjA = Tl[idxN.y];
        const uint2 ntiB = Tl[idxN.z], ntjB = Tl[idxN.w];
        const int t2 = (t + 2 < NIT) ? (t + 2) : (NIT - 1);
        const int4 idxNN = pr4[i4base + t2 * 16 + slot];

        proc2(tiA, tjA, tiB, tjB);

        tiA = ntiA; tjA = ntjA; tiB = ntiB; tjB = ntjB;
        idxN = idxNN;
    }

    __syncthreads();                           // done reading staged T

    // reduce scratch aliases stage buffer: [slot][k][s] = lds[slot*136+k*17+s]
    #pragma unroll
    for (int m = 0; m < 4; ++m) {
        lds[slot * 136 + (2 * m)     * 17 + s] = accA[m].x + accB[m].x;  // d = s+32m
        lds[slot * 136 + (2 * m + 1) * 17 + s] = accA[m].y + accB[m].y;  // d = s+32m+16
    }
    __syncthreads();
    if (tid < 128) {
        const int ss = tid & 15, kk = tid >> 4;   // d = ss + 16*kk == tid
        float sum = 0.f;
        #pragma unroll
        for (int q = 0; q < 16; ++q) sum += lds[q * 136 + kk * 17 + ss];
        part[((size_t)b * S_CHUNKS + chunk) * 128 + tid] = sum;
    }
}

// ---------------------------------------------------------------------------
// Kernel 2: reduce partials -> sdi, MLP head + mem logits.
// ---------------------------------------------------------------------------
__global__ __launch_bounds__(256) void head_kernel(
        const float* __restrict__ part,
        const float* __restrict__ Wm1, const float* __restrict__ bm1,
        const float* __restrict__ Wm2, const float* __restrict__ bm2,
        const float* __restrict__ mem,
        float* __restrict__ out_logits, float* __restrict__ out_sdi) {
    const int b = blockIdx.x;
    const int t = threadIdx.x;
    __shared__ float s[128];
    __shared__ float h[128];

    if (t < 128) {
        float sv = 0.f;
        #pragma unroll
        for (int k = 0; k < S_CHUNKS; ++k)
            sv += part[((size_t)b * S_CHUNKS + k) * 128 + t];
        sv *= (1.f / (2.f * P));
        s[t] = sv;
        out_sdi[(size_t)b * 128 + t] = sv;
    }
    __syncthreads();
    if (t < 128) {
        float a = bm1[t];
        for (int d = 0; d < 128; ++d) a = fmaf(s[d], Wm1[d * 128 + t], a);
        h[t] = fmaxf(a, 0.f);
    }
    __syncthreads();
    if (t < 16 * C) {                       // 160 threads: 16 lanes per class
        const int c = t >> 4, l = t & 15;
        float lg = 0.f;
        #pragma unroll
        for (int q = 0; q < 8; ++q) {
            const int d = l + 16 * q;
            lg = fmaf(s[d], mem[c * 128 + d], fmaf(h[d], Wm2[d * C + c], lg));
        }
        lg = red16(lg);
        if (l == 0) out_logits[(size_t)b * C + c] = lg + bm2[c];
    }
}

extern "C" void kernel_launch(void* const* d_in, const int* in_sizes, int n_in,
                              void* d_out, int out_size, void* d_ws, size_t ws_size,
                              hipStream_t stream) {
    const float* X     = (const float*)d_in[0];
    const int*   pairs = (const int*)  d_in[1];
    const float* W1    = (const float*)d_in[2];
    const float* b1    = (const float*)d_in[3];
    const float* gamma = (const float*)d_in[4];
    const float* beta  = (const float*)d_in[5];
    const float* Wm1   = (const float*)d_in[6];
    const float* bm1   = (const float*)d_in[7];
    const float* Wm2   = (const float*)d_in[8];
    const float* bm2   = (const float*)d_in[9];
    const float* mem   = (const float*)d_in[10];

    float* out = (float*)d_out;
    float* part = (float*)d_ws;                // B*S_CHUNKS*128 floats (512 KB)

    fused_kernel<<<dim3(B, S_CHUNKS), 256, 0, stream>>>(X, W1, b1, gamma, beta,
                                                        pairs, part);
    head_kernel<<<B, 256, 0, stream>>>(part, Wm1, bm1, Wm2, bm2, mem,
                                       out, out + (size_t)B * C);
}